// Round 14
// baseline (465.177 us; speedup 1.0000x reference)
//
#include <hip/hip_runtime.h>
#include <hip/hip_bf16.h>

// ---------------------------------------------------------------------------
// GCN 2-layer as ONE persistent kernel with DIY device-scope barriers.
// Grid=512, __launch_bounds__(256,2): 2 blocks/CU x 256 CU = 512 slots >= grid
// -> all blocks co-resident (LDS 24.6KB -> 49KB/CU of 160KB; VGPR<=256). [G16]
// Phases (math identical to r13):
//   P1  prep: xb=bf16(x), deg atomics, W1t/W2t transposes          [all]
//   split: blocks[0,128)  : P2a chunk-scan | P2b sum-scan | P2c bases | P3 fill
//          blocks[128,512): gemm1 h1w = xb @ W1t   (overlapped!)
//   P5  aggln1: h1b = bf16(relu(LN(A@h1w + b1)))                   [all]
//   P6  gemm2:  h2w = bf16(h1b @ W2t)                              [all]
//   P7  aggln2: out = relu(LN(A@h2w + b2))  f32                    [all]
// Barriers: fresh counter each (zeroed by the deg memset), threadfence
// release/acquire around device-scope atomicAdd arrive + spin.
// 2 graph nodes total: memset(deg+bar), mega_kernel.
// ---------------------------------------------------------------------------

typedef __attribute__((ext_vector_type(8))) short bf16x8;
typedef __attribute__((ext_vector_type(4))) float f32x4;
typedef __attribute__((ext_vector_type(4))) unsigned short us4;
typedef __attribute__((ext_vector_type(8))) unsigned short us8;

template <int CW> struct VecT;
template <> struct VecT<4> { typedef us4 T; };
template <> struct VecT<8> { typedef us8 T; };

#define GRID 512
#define BLK 256
#define CSRB 128  // blocks running the CSR-build chain in the split phase

__device__ __forceinline__ unsigned short f2bf(float f) {  // RNE f32->bf16
  unsigned int x = __float_as_uint(f);
  return (unsigned short)((x + 0x7FFFu + ((x >> 16) & 1u)) >> 16);
}
__device__ __forceinline__ float bf2f(unsigned short u) {
  return __uint_as_float((unsigned int)u << 16);
}

struct Params {
  const float* x; const int* src; const int* dst;
  const float* W1; const float* b1; const float* ga1; const float* be1;
  const float* W2; const float* b2; const float* ga2; const float* be2;
  float* out;
  unsigned short* xb; unsigned short* h1w; unsigned short* h1b; unsigned short* h2w;
  unsigned short* W1t; unsigned short* W2t;
  int* deg; int* curs; int* offs; float* dinv; int2* csr; int* bsum; int* bar;
  int N, E, Cin, Ch, Cout;
};

// device-scope arrive+spin barrier; one FRESH (pre-zeroed) counter per use.
__device__ __forceinline__ void bar_sync(int* ctr, int target) {
  __syncthreads();
  if (threadIdx.x == 0) {
    __threadfence();                       // release all prior writes
    atomicAdd(ctr, 1);
    while (atomicAdd(ctr, 0) < target) __builtin_amdgcn_s_sleep(2);
    __threadfence();                       // acquire
  }
  __syncthreads();
}

// ------------------------- phase helper bodies -----------------------------

__device__ __forceinline__ void transpose_tile(const float* __restrict__ W,
                                               unsigned short* __restrict__ Wt,
                                               int K, int N, int n0, int k0,
                                               unsigned short (*t)[33], int tid) {
  int tx = tid & 31, ty = tid >> 5;  // ty 0..7
#pragma unroll
  for (int i = 0; i < 32; i += 8)
    t[ty + i][tx] = f2bf(W[(size_t)(k0 + ty + i) * N + n0 + tx]);
  __syncthreads();
#pragma unroll
  for (int i = 0; i < 32; i += 8)
    Wt[(size_t)(n0 + ty + i) * K + k0 + tx] = t[tx][ty + i];
  __syncthreads();
}

// one 64x128 bf16-out GEMM tile, LDS double-buffered (r13-proven body).
__device__ __forceinline__ void gemm_tile(const unsigned short* __restrict__ A,
                                          const unsigned short* __restrict__ Bt,
                                          unsigned short* __restrict__ C,
                                          int M, int K, int Nn, int bm, int bn,
                                          unsigned short* As, unsigned short* Bs,
                                          int tid) {
  int lane = tid & 63, wid = tid >> 6;
  int wm = (wid >> 1) * 32, wn = (wid & 1) * 64;
  int srow = tid >> 2;
  int schunk = tid & 3;
  int frow = lane & 15, fk = lane >> 4;
  f32x4 acc[2][4] = {};

  int scA = schunk ^ ((srow >> 1) & 3);
  int gaA = bm + srow; gaA = gaA < M ? gaA : M - 1;
  const unsigned short* gA0 = A + (size_t)gaA * K + scA * 8;
  int rowB0 = srow, rowB1 = 64 + srow;
  int scB0 = schunk ^ ((rowB0 >> 1) & 3);
  int scB1 = schunk ^ ((rowB1 >> 1) & 3);
  const unsigned short* gB0 = Bt + (size_t)(bn + rowB0) * K + scB0 * 8;
  const unsigned short* gB1 = Bt + (size_t)(bn + rowB1) * K + scB1 * 8;

  auto stage = [&](int k0, unsigned short* Ad, unsigned short* Bd) {
    __builtin_amdgcn_global_load_lds(
        (const __attribute__((address_space(1))) unsigned int*)(const void*)(gA0 + k0),
        (__attribute__((address_space(3))) unsigned int*)(void*)(Ad + (wid * 16) * 32),
        16, 0, 0);
    __builtin_amdgcn_global_load_lds(
        (const __attribute__((address_space(1))) unsigned int*)(const void*)(gB0 + k0),
        (__attribute__((address_space(3))) unsigned int*)(void*)(Bd + (wid * 16) * 32),
        16, 0, 0);
    __builtin_amdgcn_global_load_lds(
        (const __attribute__((address_space(1))) unsigned int*)(const void*)(gB1 + k0),
        (__attribute__((address_space(3))) unsigned int*)(void*)(Bd + (64 + wid * 16) * 32),
        16, 0, 0);
  };

  int nk = K >> 5;
  stage(0, As, Bs);
  __syncthreads();
  for (int k = 0; k < nk; ++k) {
    unsigned short* Ac = As + (k & 1) * 64 * 32;
    unsigned short* Bc = Bs + (k & 1) * 128 * 32;
    if (k + 1 < nk)
      stage((k + 1) << 5, As + ((k + 1) & 1) * 64 * 32, Bs + ((k + 1) & 1) * 128 * 32);
    bf16x8 af[2], bf[4];
#pragma unroll
    for (int mi = 0; mi < 2; ++mi) {
      int row = wm + mi * 16 + frow;
      int sc = fk ^ ((row >> 1) & 3);
      af[mi] = *(const bf16x8*)(Ac + row * 32 + sc * 8);
    }
#pragma unroll
    for (int ni = 0; ni < 4; ++ni) {
      int row = wn + ni * 16 + frow;
      int sc = fk ^ ((row >> 1) & 3);
      bf[ni] = *(const bf16x8*)(Bc + row * 32 + sc * 8);
    }
#pragma unroll
    for (int mi = 0; mi < 2; ++mi)
#pragma unroll
      for (int ni = 0; ni < 4; ++ni)
        acc[mi][ni] = __builtin_amdgcn_mfma_f32_16x16x32_bf16(af[mi], bf[ni], acc[mi][ni], 0, 0, 0);
    __syncthreads();  // implicit vmcnt(0) drain: next buffers landed
  }

  int row0 = bm + wm + fk * 4;
  int col0 = bn + wn + frow;
#pragma unroll
  for (int mi = 0; mi < 2; ++mi) {
#pragma unroll
    for (int ni = 0; ni < 4; ++ni) {
      int col = col0 + ni * 16;
#pragma unroll
      for (int r = 0; r < 4; ++r) {
        int row = row0 + mi * 16 + r;
        if (row < M) C[(size_t)row * Nn + col] = f2bf(acc[mi][ni][r]);
      }
    }
  }
}

// wave-per-node aggregation + bias + LN + ReLU (r13-proven body).
template <int C, typename OutT>
__device__ __forceinline__ void aggln_node(int node, int lane,
                                           const unsigned short* __restrict__ H,
                                           const int2* __restrict__ csr,
                                           const int* __restrict__ offs,
                                           const float* __restrict__ dinv,
                                           const float* __restrict__ bias,
                                           const float* __restrict__ gamma,
                                           const float* __restrict__ beta,
                                           OutT* __restrict__ out) {
  constexpr int CW = C / 64;
  typedef typename VecT<CW>::T usv;
  int p0 = offs[node], p1 = offs[node + 1];
  int n = p1 - p0;
  float acc[CW] = {};
  auto fma_row = [&](usv hv, float wt) {
#pragma unroll
    for (int j = 0; j < CW; ++j) acc[j] = fmaf(bf2f(hv[j]), wt, acc[j]);
  };
  if (n > 0) {
    int2 e0 = csr[p0];
    usv h0 = *(const usv*)&H[(size_t)e0.x * C + lane * CW];
    if (n > 1) {
      int2 e1 = csr[p0 + 1];
      for (int p = p0; p + 2 < p1; ++p) {
        usv h1v = *(const usv*)&H[(size_t)e1.x * C + lane * CW];
        int2 e2 = csr[p + 2];
        fma_row(h0, __int_as_float(e0.y));
        e0 = e1; h0 = h1v; e1 = e2;
      }
      usv h1v = *(const usv*)&H[(size_t)e1.x * C + lane * CW];
      fma_row(h0, __int_as_float(e0.y));
      fma_row(h1v, __int_as_float(e1.y));
    } else {
      fma_row(h0, __int_as_float(e0.y));
    }
  }
  float dn = dinv[node];
  usv sv = *(const usv*)&H[(size_t)node * C + lane * CW];
  fma_row(sv, dn * dn);  // self loop
#pragma unroll
  for (int j = 0; j < CW; ++j) acc[j] += bias[lane * CW + j];
  float s = 0.f, ss = 0.f;
#pragma unroll
  for (int j = 0; j < CW; ++j) { s += acc[j]; ss += acc[j] * acc[j]; }
#pragma unroll
  for (int off = 32; off > 0; off >>= 1) {
    s  += __shfl_xor(s, off, 64);
    ss += __shfl_xor(ss, off, 64);
  }
  float mu = s * (1.0f / C);
  float var = ss * (1.0f / C) - mu * mu;
  float r = rsqrtf(var + 1e-5f);
  float o[CW];
#pragma unroll
  for (int j = 0; j < CW; ++j)
    o[j] = fmaxf((acc[j] - mu) * r * gamma[lane * CW + j] + beta[lane * CW + j], 0.f);
  if constexpr (sizeof(OutT) == 4) {
#pragma unroll
    for (int j = 0; j < CW; ++j) out[(size_t)node * C + lane * CW + j] = o[j];
  } else {
    usv ov;
#pragma unroll
    for (int j = 0; j < CW; ++j) ov[j] = f2bf(o[j]);
    *(usv*)&out[(size_t)node * C + lane * CW] = ov;
  }
}

// ------------------------------ megakernel ---------------------------------

__global__ __launch_bounds__(BLK, 2) void mega_kernel(Params p) {
  __shared__ __align__(16) unsigned short As[2 * 64 * 32];   // 8 KB
  __shared__ __align__(16) unsigned short Bs[2 * 128 * 32];  // 16 KB
  const int bid = blockIdx.x, tid = threadIdx.x;
  const int lane = tid & 63, wid = tid >> 6;
  const int N = p.N, E = p.E, Cin = p.Cin, Ch = p.Ch, Cout = p.Cout;
  const int nch = (N + 31) >> 5;

  // P1: xb = bf16(x), deg atomics (deg pre-zeroed by memset), W transposes
  {
    long nc8 = (long)N * Cin / 8;
    for (long c = (long)bid * BLK + tid; c < nc8; c += (long)GRID * BLK) {
      long i = c * 8;
      f32x4 a = *(const f32x4*)&p.x[i];
      f32x4 b = *(const f32x4*)&p.x[i + 4];
      us8 o;
      o[0] = f2bf(a.x); o[1] = f2bf(a.y); o[2] = f2bf(a.z); o[3] = f2bf(a.w);
      o[4] = f2bf(b.x); o[5] = f2bf(b.y); o[6] = f2bf(b.z); o[7] = f2bf(b.w);
      *(us8*)&p.xb[i] = o;
    }
    for (int e = bid * BLK + tid; e < E; e += GRID * BLK)
      atomicAdd(&p.deg[p.dst[e]], 1);
    int nbw1 = (Cin >> 5) * (Ch >> 5), nbw2 = (Ch >> 5) * (Cout >> 5);
    unsigned short (*tt)[33] = (unsigned short(*)[33])As;
    for (int ti = bid; ti < nbw1 + nbw2; ti += GRID) {
      if (ti < nbw1) { int w = Ch >> 5; transpose_tile(p.W1, p.W1t, Cin, Ch, (ti % w) * 32, (ti / w) * 32, tt, tid); }
      else { int t2 = ti - nbw1; int w = Cout >> 5; transpose_tile(p.W2, p.W2t, Ch, Cout, (t2 % w) * 32, (t2 / w) * 32, tt, tid); }
    }
  }
  bar_sync(p.bar + 0, GRID);

  // split: CSR chain on blocks [0,CSRB) overlapped with gemm1 on the rest
  if (bid < CSRB) {
    // P2a: per-32-node chunk local exclusive scan + dinv
    for (int c = bid * 4 + wid; c < nch; c += CSRB * 4) {
      if (lane < 32) {
        int i = (c << 5) + lane;
        int v = (i < N) ? p.deg[i] : 0;
        if (i < N) p.dinv[i] = rsqrtf((float)(v + 1));  // +1 self loop
        int s = v;
#pragma unroll
        for (int off = 1; off < 32; off <<= 1) {
          int u = __shfl_up(s, off, 64);
          if (lane >= off) s += u;
        }
        if (i < N) p.offs[i] = s - v;   // local exclusive
        if (lane == 31) p.bsum[c] = s;  // chunk total
      }
    }
    bar_sync(p.bar + 1, CSRB);
    // P2b: block 0 wave 0 scans chunk totals (exclusive)
    if (bid == 0 && wid == 0) {
      int base = 0;
      for (int c0 = 0; c0 < nch; c0 += 64) {
        int idx = c0 + lane;
        int v = (idx < nch) ? p.bsum[idx] : 0;
        int s = v;
#pragma unroll
        for (int off = 1; off < 64; off <<= 1) {
          int u = __shfl_up(s, off, 64);
          if (lane >= off) s += u;
        }
        if (idx < nch) p.bsum[idx] = base + s - v;
        base += __shfl(s, 63, 64);
      }
      if (lane == 0) p.offs[N] = base;  // = E
    }
    bar_sync(p.bar + 2, CSRB);
    // P2c: add chunk bases, init cursors
    for (int c = bid * 4 + wid; c < nch; c += CSRB * 4) {
      if (lane < 32) {
        int i = (c << 5) + lane;
        if (i < N) {
          int o = p.offs[i] + p.bsum[c];
          p.offs[i] = o;
          p.curs[i] = o;
        }
      }
    }
    bar_sync(p.bar + 3, CSRB);
    // P3: CSR fill
    for (int e = bid * BLK + tid; e < E; e += CSRB * BLK) {
      int s = p.src[e], d = p.dst[e];
      int pos = atomicAdd(&p.curs[d], 1);
      p.csr[pos] = make_int2(s, __float_as_int(p.dinv[s] * p.dinv[d]));
    }
  } else {
    // gemm1: h1w = xb @ W1t (only needs P1 outputs -> overlaps CSR chain)
    int tm = (N + 63) >> 6, nt = tm * (Ch >> 7);
    for (int t = bid - CSRB; t < nt; t += GRID - CSRB)
      gemm_tile(p.xb, p.W1t, p.h1w, N, Cin, Ch, (t % tm) * 64, (t / tm) * 128, As, Bs, tid);
  }
  bar_sync(p.bar + 4, GRID);

  // P5: aggln1 -> h1b (bf16)
  for (int node = bid * 4 + wid; node < N; node += GRID * 4)
    aggln_node<512, unsigned short>(node, lane, p.h1w, p.csr, p.offs, p.dinv,
                                    p.b1, p.ga1, p.be1, p.h1b);
  bar_sync(p.bar + 5, GRID);

  // P6: gemm2: h2w = h1b @ W2t
  {
    int tm = (N + 63) >> 6, nt = tm * (Cout >> 7);
    for (int t = bid; t < nt; t += GRID)
      gemm_tile(p.h1b, p.W2t, p.h2w, N, Ch, Cout, (t % tm) * 64, (t / tm) * 128, As, Bs, tid);
  }
  bar_sync(p.bar + 6, GRID);

  // P7: aggln2 -> out (f32)
  for (int node = bid * 4 + wid; node < N; node += GRID * 4)
    aggln_node<256, float>(node, lane, p.h2w, p.csr, p.offs, p.dinv,
                           p.b2, p.ga2, p.be2, p.out);
}

// ------------------------------ launcher -----------------------------------

extern "C" void kernel_launch(void* const* d_in, const int* in_sizes, int n_in,
                              void* d_out, int out_size, void* d_ws, size_t ws_size,
                              hipStream_t stream) {
  const float* x    = (const float*)d_in[0];
  const int*   ei   = (const int*)d_in[1];
  const float* W1   = (const float*)d_in[2];
  const float* b1   = (const float*)d_in[3];
  const float* ga1  = (const float*)d_in[4];
  const float* be1  = (const float*)d_in[5];
  const float* W2   = (const float*)d_in[6];
  const float* b2   = (const float*)d_in[7];
  const float* ga2  = (const float*)d_in[8];
  const float* be2  = (const float*)d_in[9];
  float* out = (float*)d_out;

  const int Ch   = in_sizes[3];        // 512
  const int Cout = in_sizes[7];        // 256
  const int Cin  = in_sizes[2] / Ch;   // 256
  const int N    = in_sizes[0] / Cin;  // 10000
  const int E    = in_sizes[1] / 2;    // 160000
  const int* srcp = ei;
  const int* dstp = ei + E;
  const int nch = (N + 31) >> 5;

  char* ws = (char*)d_ws;
  size_t off = 0;
  auto alloc = [&](size_t bytes) -> void* {
    off = (off + 255) & ~(size_t)255;
    void* p = ws + off;
    off += bytes;
    return p;
  };
  unsigned short* xb   = (unsigned short*)alloc((size_t)N * Cin * 2);
  unsigned short* h1w  = (unsigned short*)alloc((size_t)N * Ch * 2);
  unsigned short* h1b  = (unsigned short*)alloc((size_t)N * Ch * 2);
  unsigned short* h2w  = (unsigned short*)alloc((size_t)N * Cout * 2);
  unsigned short* W1t  = (unsigned short*)alloc((size_t)Cin * Ch * 2);
  unsigned short* W2t  = (unsigned short*)alloc((size_t)Ch * Cout * 2);
  int*   degbar = (int*)alloc((size_t)(N + 32) * 4);  // deg[N] + bar[32], one memset
  int*   deg = degbar;
  int*   bar = degbar + N;
  int*   curs  = (int*)alloc((size_t)N * 4);
  int*   offs  = (int*)alloc((size_t)(N + 1) * 4);
  float* dinv  = (float*)alloc((size_t)N * 4);
  int2*  csr   = (int2*)alloc((size_t)E * 8);
  int*   bsum  = (int*)alloc((size_t)(nch + 1) * 4);

  hipMemsetAsync(degbar, 0, (size_t)(N + 32) * 4, stream);

  Params p;
  p.x = x; p.src = srcp; p.dst = dstp;
  p.W1 = W1; p.b1 = b1; p.ga1 = ga1; p.be1 = be1;
  p.W2 = W2; p.b2 = b2; p.ga2 = ga2; p.be2 = be2;
  p.out = out;
  p.xb = xb; p.h1w = h1w; p.h1b = h1b; p.h2w = h2w;
  p.W1t = W1t; p.W2t = W2t;
  p.deg = deg; p.curs = curs; p.offs = offs; p.dinv = dinv;
  p.csr = csr; p.bsum = bsum; p.bar = bar;
  p.N = N; p.E = E; p.Cin = Cin; p.Ch = Ch; p.Cout = Cout;

  mega_kernel<<<GRID, BLK, 0, stream>>>(p);
}